// Round 1
// baseline (120.831 us; speedup 1.0000x reference)
//
#include <hip/hip_runtime.h>
#include <hip/hip_fp16.h>

// QLinear with per-k fp16 requantized accumulation (mptorch fma semantics).
// out = q16( q16_scan_fma( q8(x) @ q8(W)^T ) + q8(b) )
//   q8  = E4M3 quant (emin=-6, max 240, RNE, subnormals)  — software, exact
//   q16 = E5M10 quant == IEEE fp16 RNE (+sat 65504, unreachable here)
// Key: v_pk_fma_f16 (single RNE rounding of exact a*b+c) is bit-identical to
// the reference's fp32-mul/fp32-add/quant chain because the fp32 add is exact
// for |acc| < 64 (data max ~6).

#define M_DIM 2048
#define N_DIM 1024
#define K_DIM 1024

#define BM 32
#define BN 128
#define BK 64

// exact E4M3 (exp=4, man=3) quantization of an fp32 value, result fp32
__device__ __forceinline__ float quant_e4m3(float v) {
  unsigned au = __float_as_uint(v) & 0x7fffffffu;
  if (au == 0u) return v;                 // +-0
  int e = (int)(au >> 23) - 127;          // floor(log2|v|) for normals;
  if (e < -6) e = -6;                     // fp32 subnorms hit the clamp too
  float s  = __uint_as_float((unsigned)(130 - e) << 23);  // 2^(3-e), exact
  float is = __uint_as_float((unsigned)(124 + e) << 23);  // 2^(e-3), exact
  float r = rintf(v * s) * is;            // RNE (half-to-even), all steps exact
  return fminf(240.f, fmaxf(-240.f, r));
}

// in [R][C] fp32 -> out [C][R] fp16 (E4M3-quantized; E4M3 values are fp16-exact)
__global__ __launch_bounds__(256) void qt_kernel(const float* __restrict__ in,
                                                 __half* __restrict__ outp,
                                                 int R, int C) {
  __shared__ float tile[32][33];
  const int tx = threadIdx.x & 31;
  const int ty = threadIdx.x >> 5;
  const int c0 = blockIdx.x * 32;
  const int r0 = blockIdx.y * 32;
#pragma unroll
  for (int i = 0; i < 4; i++) {
    int r = r0 + ty + i * 8;
    tile[ty + i * 8][tx] = quant_e4m3(in[(size_t)r * C + c0 + tx]);
  }
  __syncthreads();
#pragma unroll
  for (int i = 0; i < 4; i++) {
    int c = c0 + ty + i * 8;
    outp[(size_t)c * R + r0 + tx] = __float2half(tile[tx][ty + i * 8]);
  }
}

__global__ __launch_bounds__(256) void qbias_kernel(const float* __restrict__ b,
                                                    float* __restrict__ qb) {
  int i = blockIdx.x * 256 + threadIdx.x;
  qb[i] = quant_e4m3(b[i]);
}

// xT [K][M] fp16, wT [K][N] fp16, qb [N] fp32, out [M][N] fp32
// block tile 32(m) x 128(n), thread tile 4x4, K staged in BK=64 chunks.
__global__ __launch_bounds__(256, 2) void gemm_qfma(const __half* __restrict__ xT,
                                                    const __half* __restrict__ wT,
                                                    const float* __restrict__ qb,
                                                    float* __restrict__ outp) {
  __shared__ unsigned xs[BK][BM];       // x splatted to both halves (8 KB)
  __shared__ unsigned wsh[BK][BN / 2];  // w as half2 {n, n+1}       (16 KB)
  const int tid = threadIdx.x;
  const int tn = tid & 31;   // 32 n-threads * 4 = BN
  const int tm = tid >> 5;   //  8 m-threads * 4 = BM
  const int bn0 = blockIdx.x * BN;
  const int bm0 = blockIdx.y * BM;

  __half2 acc[4][2];
#pragma unroll
  for (int i = 0; i < 4; i++)
#pragma unroll
    for (int j = 0; j < 2; j++) acc[i][j] = __float2half2_rn(0.0f);

  const int xr = tid >> 2;          // 0..63  (k row)
  const int xc = (tid & 3) << 3;    // 0,8,16,24 (m col, 8 halfs)
  const int wc = (tid & 15) << 3;   // 0..120 (n col, 8 halfs)
  const int wr = tid >> 4;          // 0..15  (k row base)

  for (int kc = 0; kc < K_DIM; kc += BK) {
    __syncthreads();  // protect previous chunk's reads
    {
      // stage x: 64 k-rows x 32 m, splat each half into a uint
      uint4 v = *reinterpret_cast<const uint4*>(xT + (size_t)(kc + xr) * M_DIM + bm0 + xc);
      unsigned* d = &xs[xr][xc];
      d[0] = (v.x & 0xffffu) * 0x10001u;
      d[1] = (v.x >> 16)     * 0x10001u;
      d[2] = (v.y & 0xffffu) * 0x10001u;
      d[3] = (v.y >> 16)     * 0x10001u;
      d[4] = (v.z & 0xffffu) * 0x10001u;
      d[5] = (v.z >> 16)     * 0x10001u;
      d[6] = (v.w & 0xffffu) * 0x10001u;
      d[7] = (v.w >> 16)     * 0x10001u;
    }
#pragma unroll
    for (int p = 0; p < 4; p++) {
      // stage w: 64 k-rows x 128 n, contiguous b128 copies
      const int r = wr + (p << 4);
      *reinterpret_cast<uint4*>(&wsh[r][wc >> 1]) =
          *reinterpret_cast<const uint4*>(wT + (size_t)(kc + r) * N_DIM + bn0 + wc);
    }
    __syncthreads();
#pragma unroll
    for (int kk = 0; kk < BK; kk++) {   // strictly ascending k: scan order
      const uint4 xv = *reinterpret_cast<const uint4*>(&xs[kk][tm << 2]);
      const uint2 wv = *reinterpret_cast<const uint2*>(&wsh[kk][tn << 1]);
      const __half2 w0 = *reinterpret_cast<const __half2*>(&wv.x);
      const __half2 w1 = *reinterpret_cast<const __half2*>(&wv.y);
      const __half2 x0 = *reinterpret_cast<const __half2*>(&xv.x);
      const __half2 x1 = *reinterpret_cast<const __half2*>(&xv.y);
      const __half2 x2 = *reinterpret_cast<const __half2*>(&xv.z);
      const __half2 x3 = *reinterpret_cast<const __half2*>(&xv.w);
      acc[0][0] = __hfma2(x0, w0, acc[0][0]);
      acc[0][1] = __hfma2(x0, w1, acc[0][1]);
      acc[1][0] = __hfma2(x1, w0, acc[1][0]);
      acc[1][1] = __hfma2(x1, w1, acc[1][1]);
      acc[2][0] = __hfma2(x2, w0, acc[2][0]);
      acc[2][1] = __hfma2(x2, w1, acc[2][1]);
      acc[3][0] = __hfma2(x3, w0, acc[3][0]);
      acc[3][1] = __hfma2(x3, w1, acc[3][1]);
    }
  }

  // epilogue: out = fp16RNE(acc + qb), stored fp32. fp32 add is exact here.
  const float4 bv = *reinterpret_cast<const float4*>(qb + bn0 + (tn << 2));
#pragma unroll
  for (int i = 0; i < 4; i++) {
    float4 o;
    o.x = __half2float(__float2half(__low2float(acc[i][0])  + bv.x));
    o.y = __half2float(__float2half(__high2float(acc[i][0]) + bv.y));
    o.z = __half2float(__float2half(__low2float(acc[i][1])  + bv.z));
    o.w = __half2float(__float2half(__high2float(acc[i][1]) + bv.w));
    *reinterpret_cast<float4*>(outp + (size_t)(bm0 + (tm << 2) + i) * N_DIM + bn0 + (tn << 2)) = o;
  }
}

extern "C" void kernel_launch(void* const* d_in, const int* in_sizes, int n_in,
                              void* d_out, int out_size, void* d_ws, size_t ws_size,
                              hipStream_t stream) {
  const float* x = (const float*)d_in[0];   // [2048][1024]
  const float* w = (const float*)d_in[1];   // [1024][1024] (out_f, in_f)
  const float* b = (const float*)d_in[2];   // [1024]
  float* outp = (float*)d_out;              // [2048][1024] fp32

  char* ws = (char*)d_ws;
  __half* xT = (__half*)ws;                        // [K][M]  4 MiB
  __half* wT = (__half*)(ws + (size_t)(4 << 20));  // [K][N]  2 MiB
  float*  qb = (float*)(ws + (size_t)(6 << 20));   // [N]     4 KiB

  hipLaunchKernelGGL(qt_kernel, dim3(K_DIM / 32, M_DIM / 32), dim3(256), 0, stream,
                     x, xT, M_DIM, K_DIM);
  hipLaunchKernelGGL(qt_kernel, dim3(K_DIM / 32, N_DIM / 32), dim3(256), 0, stream,
                     w, wT, N_DIM, K_DIM);
  hipLaunchKernelGGL(qbias_kernel, dim3(N_DIM / 256), dim3(256), 0, stream, b, qb);
  hipLaunchKernelGGL(gemm_qfma, dim3(N_DIM / BN, M_DIM / BM), dim3(256), 0, stream,
                     xT, wT, qb, outp);
}